// Round 10
// baseline (264.957 us; speedup 1.0000x reference)
//
#include <hip/hip_runtime.h>
#include <cstdint>

#define KT   2048             // C*D
#define GR   2                // batches per tile (16 KB tile)
#define NBLK 256              // 1 block per CU
#define BPB  (65536 / NBLK)   // 256 batches per block
#define NT   (BPB / GR)       // 128 tiles per block

typedef const __attribute__((address_space(1))) uint32_t gu32;
typedef __attribute__((address_space(3))) uint32_t lu32;

// W6 k-major: W6[k*2048 + j*256 + l*4 + dd] = W[jp][k][m], e = jp*32+m = (j*64+l)*4+dd
// -> a wave's (k,j) quad read is 64 lanes x 16B consecutive = coalesced 1KB
__global__ __launch_bounds__(1024) void wtrans_kernel(const float* __restrict__ W,
                                                      float* __restrict__ W6) {
    int jp = blockIdx.x;          // [0,64)
    int t = threadIdx.x;          // k*32 + m
    int k = t >> 5, m = t & 31;
    int e = jp * 32 + m;
    int e4 = e >> 2, dd = e & 3;
    int j = e4 >> 6, l = e4 & 63;
    W6[k * 2048 + j * 256 + l * 4 + dd] = W[jp * 1024 + t];
}

template <int CTRL>
__device__ __forceinline__ float dpp_add(float v) {
    int moved = __builtin_amdgcn_update_dpp(0, __float_as_int(v), CTRL, 0xF, 0xF, true);
    return v + __int_as_float(moved);
}

// 1024 threads = 16 waves = (jh in 2 j-halves) x (kq in 8 k-quads).
// W slice (4k x 4j quads) = 64 VGPR, loaded once, vmcnt-drained so the VMEM
// counter only ever holds {stage loads, out stores}. x triple-buffered in LDS,
// staged 2 tiles ahead; raw s_barrier + counted vmcnt(1): prefetch of tile
// tt+1 stays in flight across all barriers, never drained mid-loop.
__global__ __launch_bounds__(1024, 1) void ipf_kernel(const float* __restrict__ x,
                                                      const float* __restrict__ W6,
                                                      float* __restrict__ out) {
    __shared__ float xs[3][GR * KT];   // 3 x 16 KB
    __shared__ float Pp[128 * 9];      // 4.5 KB: row (w*8+g), 8 payload + 1 pad
    __shared__ float Sl[GR * 32];      // 256 B
    const int t = threadIdx.x;
    const int w = t >> 6, l = t & 63;
    const int kq = w & 7;              // k-quad [4kq, 4kq+4)
    const int jh = w >> 3;             // j-half: j in [jh*4, jh*4+4)
    const long long bbase = (long long)blockIdx.x * BPB;
    const char* gx = (const char*)(x + bbase * KT);

    // ---- W slice -> 64 VGPRs (once), then DRAIN so vmcnt counting is clean ----
    float4 Wr[4][4];
    #pragma unroll
    for (int q = 0; q < 4; ++q)
        #pragma unroll
        for (int jj = 0; jj < 4; ++jj)
            Wr[q][jj] = *(const float4*)(W6 + (kq * 4 + q) * 2048 + (jh * 4 + jj) * 256 + l * 4);
    __builtin_amdgcn_sched_barrier(0);
    asm volatile("s_waitcnt vmcnt(0)" ::: "memory");   // W loads retired; counter = 0
    __builtin_amdgcn_sched_barrier(0);

    // stage tile tt (16 KB): each wave 1 load, lane-linear LDS dest
    #define STAGE(tt, bf)                                                              \
        __builtin_amdgcn_global_load_lds(                                              \
            (gu32*)(gx + (size_t)(tt) * (GR * KT * 4) + w * 1024 + l * 16),            \
            (lu32*)((char*)xs[bf] + w * 1024), 16, 0, 0)

    STAGE(0, 0);
    STAGE(1, 1);

    int cur = 0;
    #pragma unroll 1
    for (int tt = 0; tt < NT; ++tt) {
        // (A) newest outstanding op is always stage(tt+1): vmcnt(1) => stage(tt)
        //     and all older stores retired; stage(tt+1) stays in flight.
        asm volatile("s_waitcnt vmcnt(1)" ::: "memory");
        // (B) all waves' pieces resident
        __builtin_amdgcn_s_barrier();
        __builtin_amdgcn_sched_barrier(0);

        // (C) compute: acc[bb][q] = sum over this wave's j-half
        const float* xc = xs[cur];
        float acc[GR][4];
        #pragma unroll
        for (int bb = 0; bb < GR; ++bb)
            #pragma unroll
            for (int q = 0; q < 4; ++q) acc[bb][q] = 0.0f;

        #pragma unroll
        for (int jj = 0; jj < 4; ++jj) {
            float4 xv[GR];
            #pragma unroll
            for (int bb = 0; bb < GR; ++bb)
                xv[bb] = *(const float4*)(xc + bb * KT + (jh * 4 + jj) * 256 + l * 4);
            #pragma unroll
            for (int bb = 0; bb < GR; ++bb)
                #pragma unroll
                for (int q = 0; q < 4; ++q) {
                    acc[bb][q] += xv[bb].x * Wr[q][jj].x;
                    acc[bb][q] += xv[bb].y * Wr[q][jj].y;
                    acc[bb][q] += xv[bb].z * Wr[q][jj].z;
                    acc[bb][q] += xv[bb].w * Wr[q][jj].w;
                }
        }
        // 8-lane DPP reduce -> lane (l&7)==7 holds 8-lane partial
        #pragma unroll
        for (int bb = 0; bb < GR; ++bb)
            #pragma unroll
            for (int q = 0; q < 4; ++q) {
                float v = acc[bb][q];
                v = dpp_add<0x111>(v);
                v = dpp_add<0x112>(v);
                v = dpp_add<0x114>(v);
                acc[bb][q] = v;
            }
        if ((l & 7) == 7) {
            const int g = l >> 3;
            float* row = Pp + (w * 8 + g) * 9;
            #pragma unroll
            for (int bb = 0; bb < GR; ++bb)
                *(float4*)(row + bb * 4) = make_float4(acc[bb][0], acc[bb][1], acc[bb][2], acc[bb][3]);
        }
        asm volatile("s_waitcnt lgkmcnt(0)" ::: "memory");
        __builtin_amdgcn_s_barrier();      // (D) Pp visible — NO vmcnt drain
        __builtin_amdgcn_sched_barrier(0);

        // (E) gather, distributed: wave w covers S-indices sv = w*4 + (l>>4); 16-lane groups
        {
            const int sv = w * 4 + (l >> 4);
            const int r = l & 15;                       // partial row within group
            const int bb = sv >> 5, k = sv & 31;
            const int row = ((r >> 3) * 8 + (k >> 2)) * 8 + (r & 7);   // (jh2*8+kq)*8+g
            float v = Pp[row * 9 + bb * 4 + (k & 3)];
            v = dpp_add<0x111>(v);
            v = dpp_add<0x112>(v);
            v = dpp_add<0x114>(v);
            v = dpp_add<0x118>(v);                      // row_shr:8 -> lane r==15 holds 16-sum
            if ((l & 15) == 15) Sl[sv] = v;
        }
        asm volatile("s_waitcnt lgkmcnt(0)" ::: "memory");
        __builtin_amdgcn_s_barrier();      // (F) Sl visible — NO vmcnt drain
        __builtin_amdgcn_sched_barrier(0);

        // (G) phase 2, distributed: wave w covers outs o = w*8 + (l>>3); 8-lane groups
        {
            const int g2 = l >> 3, h = l & 7;
            const int o = w * 8 + g2;                   // [0,128)
            const int bb = o >> 6, i = o & 63;
            float s = 0.0f;
            #pragma unroll
            for (int u = 0; u < 4; ++u) {
                const int dd = (h * 4 + u + i) & 31;    // bank-rotated, <=2 lanes/bank
                s += xc[bb * KT + i * 32 + dd] * Sl[bb * 32 + dd];
            }
            s = dpp_add<0x111>(s);
            s = dpp_add<0x112>(s);
            s = dpp_add<0x114>(s);                      // lane h==7 holds the dot
            const float e2 = __expf(2.0f * s);          // tanh = 1 - 2/(e^{2s}+1)
            const float r2 = 1.0f - 2.0f / (e2 + 1.0f);
            if ((l & 7) == 7)
                out[(bbase + (long long)tt * GR + bb) * 64 + i] = r2;
        }
        __builtin_amdgcn_sched_barrier(0); // keep store older than next stage (vmcnt order)

        // (H) stage tile tt+2 into the buffer freed by tile tt-1
        if (tt + 2 < NT) STAGE(tt + 2, (cur == 0) ? 2 : cur - 1);
        cur = (cur == 2) ? 0 : cur + 1;
    }
    #undef STAGE
}

extern "C" void kernel_launch(void* const* d_in, const int* in_sizes, int n_in,
                              void* d_out, int out_size, void* d_ws, size_t ws_size,
                              hipStream_t stream) {
    const float* x = (const float*)d_in[0];   // [65536,64,32] fp32
    const float* W = (const float*)d_in[1];   // [64,32,32] fp32
    float* out = (float*)d_out;               // [65536,64] fp32
    float* W6  = (float*)d_ws;                // 65536 floats = 256 KB scratch

    wtrans_kernel<<<64, 1024, 0, stream>>>(W, W6);
    ipf_kernel<<<NBLK, 1024, 0, stream>>>(x, W6, out);
}

// Round 11
// 215.167 us; speedup vs baseline: 1.2314x; 1.2314x over previous
//
#include <hip/hip_runtime.h>
#include <cstdint>

#define KT   2048             // C*D
#define GR   4                // batches per tile (32 KB tile)
#define NBLK 256              // 1 block per CU
#define BPB  (65536 / NBLK)   // 256 batches per block
#define NT   (BPB / GR)       // 64 tiles per block
#define PST  20               // Pp row stride (16B-aligned, bank-spread)

typedef const __attribute__((address_space(1))) uint32_t gu32;
typedef __attribute__((address_space(3))) uint32_t lu32;

// W6 k-major: W6[k*2048 + j*256 + l*4 + dd] = W[jp][k][m], e = jp*32+m = (j*64+l)*4+dd
__global__ __launch_bounds__(1024) void wtrans_kernel(const float* __restrict__ W,
                                                      float* __restrict__ W6) {
    int jp = blockIdx.x;          // [0,64)
    int t = threadIdx.x;          // k*32 + m
    int k = t >> 5, m = t & 31;
    int e = jp * 32 + m;
    int e4 = e >> 2, dd = e & 3;
    int j = e4 >> 6, l = e4 & 63;
    W6[k * 2048 + j * 256 + l * 4 + dd] = W[jp * 1024 + t];
}

template <int CTRL>
__device__ __forceinline__ float dpp_add(float v) {
    int moved = __builtin_amdgcn_update_dpp(0, __float_as_int(v), CTRL, 0xF, 0xF, true);
    return v + __int_as_float(moved);
}

// 1024 threads = 16 waves = (jh: 2 j-halves) x (kq: 8 k-quads). W slice = 64 VGPR, once.
// x quad-buffered in LDS (4 x 32KB), staged 2 tiles ahead, counted vmcnt (never 0 mid-loop).
// Per tile only 2 barriers: [stage | C(tt) | G(tt-1)] -> bar -> [E(tt)] -> bar(loop top).
__global__ __launch_bounds__(1024, 1) void ipf_kernel(const float* __restrict__ x,
                                                      const float* __restrict__ W6,
                                                      float* __restrict__ out) {
    extern __shared__ float smem[];
    float* xs = smem;                  // 4 * 8192 floats (4 x 32 KB)
    float* Pp = smem + 4 * 8192;       // 128 rows x PST
    float* Sl = Pp + 128 * PST;        // 128 floats: Sl[bb*32+k]
    const int t = threadIdx.x;
    const int w = t >> 6, l = t & 63;
    const int kq = w & 7;              // k-quad [4kq,4kq+4)
    const int jh = w >> 3;             // j-half [jh*4, jh*4+4)
    const long long bbase = (long long)blockIdx.x * BPB;
    const char* gx = (const char*)(x + bbase * KT);

    // ---- W slice -> 64 VGPRs, then drain so the VMEM counter is clean ----
    float4 Wr[4][4];
    #pragma unroll
    for (int q = 0; q < 4; ++q)
        #pragma unroll
        for (int jj = 0; jj < 4; ++jj)
            Wr[q][jj] = *(const float4*)(W6 + (kq * 4 + q) * 2048 + (jh * 4 + jj) * 256 + l * 4);
    __builtin_amdgcn_sched_barrier(0);
    asm volatile("s_waitcnt vmcnt(0)" ::: "memory");
    __builtin_amdgcn_sched_barrier(0);

    // stage tile tt (32 KB): wave stages 2 KB = 2 x 1KB loads (2 VMEM instrs/wave)
    #define STAGE(tt, bf)                                                                   \
        {                                                                                   \
            const char* gs = gx + (size_t)(tt) * 32768 + w * 2048;                          \
            char* ld = (char*)(xs + (bf) * 8192) + w * 2048;                                \
            __builtin_amdgcn_global_load_lds((gu32*)(gs + l * 16), (lu32*)ld, 16, 0, 0);    \
            __builtin_amdgcn_global_load_lds((gu32*)(gs + 1024 + l * 16),                   \
                                             (lu32*)(ld + 1024), 16, 0, 0);                 \
        }

    STAGE(0, 0);
    STAGE(1, 1);

    #pragma unroll 1
    for (int tt = 0; tt < NT; ++tt) {
        // (A) counted wait: stage(tt) retired; stage(tt+1) + last store stay in flight.
        //     queue(steady): [s(tt)x2, store(tt-3), s(tt+1)x2, store(tt-2)] -> vmcnt(3)
        //     tt<2: [s(tt)x2, s(tt+1)x2] -> vmcnt(2); tt=NT-1: no s(NT) -> vmcnt(2)
        if (tt >= 2 && tt < NT - 1) asm volatile("s_waitcnt vmcnt(3)" ::: "memory");
        else                        asm volatile("s_waitcnt vmcnt(2)" ::: "memory");
        __builtin_amdgcn_s_barrier();   // buf(tt) resident; Sl(tt-1) visible; Pp reusable
        __builtin_amdgcn_sched_barrier(0);

        // (B) issue stage(tt+2) first
        if (tt + 2 < NT) STAGE(tt + 2, (tt + 2) & 3);
        __builtin_amdgcn_sched_barrier(0);

        // (C) compute tile tt
        const float* xc = xs + (tt & 3) * 8192;
        float acc[GR][4];
        #pragma unroll
        for (int bb = 0; bb < GR; ++bb)
            #pragma unroll
            for (int q = 0; q < 4; ++q) acc[bb][q] = 0.0f;
        #pragma unroll
        for (int jj = 0; jj < 4; ++jj)
            #pragma unroll
            for (int bb = 0; bb < GR; ++bb) {
                const float4 xv = *(const float4*)(xc + bb * 2048 + (jh * 4 + jj) * 256 + l * 4);
                #pragma unroll
                for (int q = 0; q < 4; ++q) {
                    acc[bb][q] += xv.x * Wr[q][jj].x;
                    acc[bb][q] += xv.y * Wr[q][jj].y;
                    acc[bb][q] += xv.z * Wr[q][jj].z;
                    acc[bb][q] += xv.w * Wr[q][jj].w;
                }
            }
        #pragma unroll
        for (int bb = 0; bb < GR; ++bb)
            #pragma unroll
            for (int q = 0; q < 4; ++q) {
                float v = acc[bb][q];
                v = dpp_add<0x111>(v);
                v = dpp_add<0x112>(v);
                v = dpp_add<0x114>(v);      // lane (l&7)==7 holds 8-lane sum
                acc[bb][q] = v;
            }
        if ((l & 7) == 7) {
            float* row = Pp + (w * 8 + (l >> 3)) * PST;
            #pragma unroll
            for (int bb = 0; bb < GR; ++bb)
                *(float4*)(row + bb * 4) = make_float4(acc[bb][0], acc[bb][1], acc[bb][2], acc[bb][3]);
        }

        // (D) phase 2 of tile tt-1, same interval (independent of C)
        if (tt > 0) {
            const int tp = tt - 1;
            const float* xg = xs + (tp & 3) * 8192;
            const int o = t >> 2, h = t & 3;       // o = w*16 + (l>>2) in [0,256)
            const int bb = o >> 6, i = o & 63;
            const int qa = (i + h) & 7, qb = qa ^ 4;
            const float4 xa = *(const float4*)(xg + bb * 2048 + i * 32 + qa * 4);
            const float4 sa = *(const float4*)(Sl + bb * 32 + qa * 4);
            const float4 xv2 = *(const float4*)(xg + bb * 2048 + i * 32 + qb * 4);
            const float4 sb = *(const float4*)(Sl + bb * 32 + qb * 4);
            float s = xa.x * sa.x + xa.y * sa.y + xa.z * sa.z + xa.w * sa.w
                    + xv2.x * sb.x + xv2.y * sb.y + xv2.z * sb.z + xv2.w * sb.w;
            s = dpp_add<0x111>(s);
            s = dpp_add<0x112>(s);                 // lane h==3 holds 4-lane (8-quad) dot
            if (h == 3) {
                const float e2 = __expf(2.0f * s); // tanh = 1 - 2/(e^{2s}+1)
                out[(bbase + (long long)tp * GR + bb) * 64 + i] = 1.0f - 2.0f / (e2 + 1.0f);
            }
            __builtin_amdgcn_sched_barrier(0);     // store stays newest in VMEM queue
        }

        asm volatile("s_waitcnt lgkmcnt(0)" ::: "memory");
        __builtin_amdgcn_s_barrier();              // Pp(tt) visible — NO vmcnt drain
        __builtin_amdgcn_sched_barrier(0);

        // (E) gather: Sl[sv] = sum of 16 partials; 8-lane groups, sv = w*8 + (l>>3)
        {
            const int sv = w * 8 + (l >> 3);
            const int r = l & 7;
            const int bb = sv >> 5, k = sv & 31;
            const int rowA = (k >> 2) * 8 + r;     // jh=0; jh=1 is +64 rows
            float v = Pp[rowA * PST + bb * 4 + (k & 3)]
                    + Pp[(rowA + 64) * PST + bb * 4 + (k & 3)];
            v = dpp_add<0x111>(v);
            v = dpp_add<0x112>(v);
            v = dpp_add<0x114>(v);                 // lane r==7 holds the 8-lane sum
            if (r == 7) Sl[sv] = v;
        }
        asm volatile("s_waitcnt lgkmcnt(0)" ::: "memory");
        // loop-top barrier orders Sl writes before next interval's G reads
    }

    // epilogue: phase 2 of the last tile
    __builtin_amdgcn_s_barrier();
    {
        const int tp = NT - 1;
        const float* xg = xs + (tp & 3) * 8192;
        const int o = t >> 2, h = t & 3;
        const int bb = o >> 6, i = o & 63;
        const int qa = (i + h) & 7, qb = qa ^ 4;
        const float4 xa = *(const float4*)(xg + bb * 2048 + i * 32 + qa * 4);
        const float4 sa = *(const float4*)(Sl + bb * 32 + qa * 4);
        const float4 xv2 = *(const float4*)(xg + bb * 2048 + i * 32 + qb * 4);
        const float4 sb = *(const float4*)(Sl + bb * 32 + qb * 4);
        float s = xa.x * sa.x + xa.y * sa.y + xa.z * sa.z + xa.w * sa.w
                + xv2.x * sb.x + xv2.y * sb.y + xv2.z * sb.z + xv2.w * sb.w;
        s = dpp_add<0x111>(s);
        s = dpp_add<0x112>(s);
        if (h == 3) {
            const float e2 = __expf(2.0f * s);
            out[(bbase + (long long)tp * GR + bb) * 64 + i] = 1.0f - 2.0f / (e2 + 1.0f);
        }
    }
    #undef STAGE
}

extern "C" void kernel_launch(void* const* d_in, const int* in_sizes, int n_in,
                              void* d_out, int out_size, void* d_ws, size_t ws_size,
                              hipStream_t stream) {
    const float* x = (const float*)d_in[0];   // [65536,64,32] fp32
    const float* W = (const float*)d_in[1];   // [64,32,32] fp32
    float* out = (float*)d_out;               // [65536,64] fp32
    float* W6  = (float*)d_ws;                // 65536 floats = 256 KB scratch

    const size_t smem_bytes = (size_t)(4 * 8192 + 128 * PST + 128) * sizeof(float); // 141824
    hipFuncSetAttribute((const void*)ipf_kernel,
                        hipFuncAttributeMaxDynamicSharedMemorySize, (int)smem_bytes);

    wtrans_kernel<<<64, 1024, 0, stream>>>(W, W6);
    ipf_kernel<<<NBLK, 1024, smem_bytes, stream>>>(x, W6, out);
}

// Round 12
// 209.013 us; speedup vs baseline: 1.2677x; 1.0294x over previous
//
#include <hip/hip_runtime.h>
#include <cstdint>

#define KT   2048             // C*D
#define GR   4                // batches per tile (32 KB tile)
#define NBLK 256              // 1 block per CU
#define BPB  (65536 / NBLK)   // 256 batches per block
#define NT   (BPB / GR)       // 64 tiles per block
#define PST  20               // Pp row stride (16B-aligned, bank-spread)

typedef const __attribute__((address_space(1))) uint32_t gu32;
typedef __attribute__((address_space(3))) uint32_t lu32;

// W6 k-major: W6[k*2048 + j*256 + l*4 + dd] = W[jp][k][m], e = jp*32+m = (j*64+l)*4+dd
__global__ __launch_bounds__(1024) void wtrans_kernel(const float* __restrict__ W,
                                                      float* __restrict__ W6) {
    int jp = blockIdx.x;          // [0,64)
    int t = threadIdx.x;          // k*32 + m
    int k = t >> 5, m = t & 31;
    int e = jp * 32 + m;
    int e4 = e >> 2, dd = e & 3;
    int j = e4 >> 6, l = e4 & 63;
    W6[k * 2048 + j * 256 + l * 4 + dd] = W[jp * 1024 + t];
}

template <int CTRL>
__device__ __forceinline__ float dpp_add(float v) {
    int moved = __builtin_amdgcn_update_dpp(0, __float_as_int(v), CTRL, 0xF, 0xF, true);
    return v + __int_as_float(moved);
}

// 1024 threads = 16 waves = (jh: 2 j-halves) x (kq: 8 k-quads). W slice = 64 VGPR, once.
// x in 4 LDS buffers (4 x 32KB), staged 3 tiles ahead (96 KB in flight per CU),
// stage issued at interval END (after the barrier closing D's reads of the reused buffer).
// Counted vmcnt, never 0 mid-loop. 2 barriers per tile.
__global__ __launch_bounds__(1024, 1) void ipf_kernel(const float* __restrict__ x,
                                                      const float* __restrict__ W6,
                                                      float* __restrict__ out) {
    extern __shared__ float smem[];
    float* xs = smem;                  // 4 * 8192 floats (4 x 32 KB)
    float* Pp = smem + 4 * 8192;       // 128 rows x PST
    float* Sl = Pp + 128 * PST;        // 128 floats: Sl[bb*32+k]
    const int t = threadIdx.x;
    const int w = t >> 6, l = t & 63;
    const int kq = w & 7;              // k-quad [4kq,4kq+4)
    const int jh = w >> 3;             // j-half [jh*4, jh*4+4)
    const long long bbase = (long long)blockIdx.x * BPB;
    const char* gx = (const char*)(x + bbase * KT);

    // ---- W slice -> 64 VGPRs, then drain so the VMEM counter is clean ----
    float4 Wr[4][4];
    #pragma unroll
    for (int q = 0; q < 4; ++q)
        #pragma unroll
        for (int jj = 0; jj < 4; ++jj)
            Wr[q][jj] = *(const float4*)(W6 + (kq * 4 + q) * 2048 + (jh * 4 + jj) * 256 + l * 4);
    __builtin_amdgcn_sched_barrier(0);
    asm volatile("s_waitcnt vmcnt(0)" ::: "memory");
    __builtin_amdgcn_sched_barrier(0);

    // stage tile tt (32 KB): wave stages 2 KB = 2 x 1KB DMA loads
    #define STAGE(tt, bf)                                                                   \
        {                                                                                   \
            const char* gs = gx + (size_t)(tt) * 32768 + w * 2048;                          \
            char* ld = (char*)(xs + (bf) * 8192) + w * 2048;                                \
            __builtin_amdgcn_global_load_lds((gu32*)(gs + l * 16), (lu32*)ld, 16, 0, 0);    \
            __builtin_amdgcn_global_load_lds((gu32*)(gs + 1024 + l * 16),                   \
                                             (lu32*)(ld + 1024), 16, 0, 0);                 \
        }

    STAGE(0, 0);
    STAGE(1, 1);
    STAGE(2, 2);

    #pragma unroll 1
    for (int tt = 0; tt < NT; ++tt) {
        // (A) counted wait for stage(tt); stage(tt+1..tt+2 [+3]) + stores stay in flight.
        //     interval k issues [st(k-1), s(k+3)x2]; queue walked per tt:
        //     tt<=1:[s(tt)2 s+1 2 s+2 2]->4; tt==2:+st0 ->5; 3<=tt<=NT-3: ->6;
        //     tt==NT-2:[s2,st,s2,st]->4; tt==NT-1:[s2,st,st]->2
        if (tt >= 3 && tt < NT - 2)  asm volatile("s_waitcnt vmcnt(6)" ::: "memory");
        else if (tt == 2)            asm volatile("s_waitcnt vmcnt(5)" ::: "memory");
        else if (tt <= 1)            asm volatile("s_waitcnt vmcnt(4)" ::: "memory");
        else if (tt == NT - 2)       asm volatile("s_waitcnt vmcnt(4)" ::: "memory");
        else                         asm volatile("s_waitcnt vmcnt(2)" ::: "memory");
        __builtin_amdgcn_s_barrier();   // buf(tt) resident; Sl(tt-1) visible; Pp reusable
        __builtin_amdgcn_sched_barrier(0);

        // (B) compute tile tt — batched ds_reads (4 x b128) then 64 FMA per jj
        const float* xc = xs + (tt & 3) * 8192;
        float acc[GR][4];
        #pragma unroll
        for (int bb = 0; bb < GR; ++bb)
            #pragma unroll
            for (int q = 0; q < 4; ++q) acc[bb][q] = 0.0f;
        #pragma unroll
        for (int jj = 0; jj < 4; ++jj) {
            float4 xv[GR];
            #pragma unroll
            for (int bb = 0; bb < GR; ++bb)
                xv[bb] = *(const float4*)(xc + bb * 2048 + (jh * 4 + jj) * 256 + l * 4);
            #pragma unroll
            for (int bb = 0; bb < GR; ++bb)
                #pragma unroll
                for (int q = 0; q < 4; ++q) {
                    acc[bb][q] += xv[bb].x * Wr[q][jj].x;
                    acc[bb][q] += xv[bb].y * Wr[q][jj].y;
                    acc[bb][q] += xv[bb].z * Wr[q][jj].z;
                    acc[bb][q] += xv[bb].w * Wr[q][jj].w;
                }
        }
        #pragma unroll
        for (int bb = 0; bb < GR; ++bb)
            #pragma unroll
            for (int q = 0; q < 4; ++q) {
                float v = acc[bb][q];
                v = dpp_add<0x111>(v);
                v = dpp_add<0x112>(v);
                v = dpp_add<0x114>(v);      // lane (l&7)==7 holds 8-lane sum
                acc[bb][q] = v;
            }
        if ((l & 7) == 7) {
            float* row = Pp + (w * 8 + (l >> 3)) * PST;
            #pragma unroll
            for (int bb = 0; bb < GR; ++bb)
                *(float4*)(row + bb * 4) = make_float4(acc[bb][0], acc[bb][1], acc[bb][2], acc[bb][3]);
        }

        // (C) phase 2 of tile tt-1, same interval (independent of B)
        if (tt > 0) {
            const int tp = tt - 1;
            const float* xg = xs + (tp & 3) * 8192;
            const int o = t >> 2, h = t & 3;       // o in [0,256) = 4bb x 64i
            const int bb = o >> 6, i = o & 63;
            const int qa = (i + h) & 7, qb = qa ^ 4;
            const float4 xa = *(const float4*)(xg + bb * 2048 + i * 32 + qa * 4);
            const float4 sa = *(const float4*)(Sl + bb * 32 + qa * 4);
            const float4 xv2 = *(const float4*)(xg + bb * 2048 + i * 32 + qb * 4);
            const float4 sb = *(const float4*)(Sl + bb * 32 + qb * 4);
            float s = xa.x * sa.x + xa.y * sa.y + xa.z * sa.z + xa.w * sa.w
                    + xv2.x * sb.x + xv2.y * sb.y + xv2.z * sb.z + xv2.w * sb.w;
            s = dpp_add<0x111>(s);
            s = dpp_add<0x112>(s);                 // lane h==3 holds 8-quad dot
            if (h == 3) {
                const float e2 = __expf(2.0f * s); // tanh = 1 - 2/(e^{2s}+1)
                out[(bbase + (long long)tp * GR + bb) * 64 + i] = 1.0f - 2.0f / (e2 + 1.0f);
            }
        }

        asm volatile("s_waitcnt lgkmcnt(0)" ::: "memory");
        __builtin_amdgcn_s_barrier();              // Pp(tt) visible; D-reads of reused buf done
        __builtin_amdgcn_sched_barrier(0);

        // (D) gather: Sl[sv] = sum of 16 partials; 8-lane groups, sv = w*8 + (l>>3)
        {
            const int sv = w * 8 + (l >> 3);
            const int r = l & 7;
            const int bb = sv >> 5, k = sv & 31;
            const int rowA = (k >> 2) * 8 + r;     // jh=0 rows; jh=1 is +64
            float v = Pp[rowA * PST + bb * 4 + (k & 3)]
                    + Pp[(rowA + 64) * PST + bb * 4 + (k & 3)];
            v = dpp_add<0x111>(v);
            v = dpp_add<0x112>(v);
            v = dpp_add<0x114>(v);                 // lane r==7 holds the 8-lane sum
            if (r == 7) Sl[sv] = v;
        }
        asm volatile("s_waitcnt lgkmcnt(0)" ::: "memory");

        // (E) stage tile tt+3 into buf[(tt+3)&3] — safe: D(tt-1)'s reads of this
        //     buffer drained before the barrier above; issued as newest VMEM ops.
        if (tt + 3 < NT) STAGE(tt + 3, (tt + 3) & 3);
        __builtin_amdgcn_sched_barrier(0);
        // loop-top barrier orders Sl writes before next interval's phase-2 reads
    }

    // epilogue: phase 2 of the last tile (buffer (NT-1)&3 untouched since its compute)
    __builtin_amdgcn_s_barrier();
    {
        const int tp = NT - 1;
        const float* xg = xs + (tp & 3) * 8192;
        const int o = t >> 2, h = t & 3;
        const int bb = o >> 6, i = o & 63;
        const int qa = (i + h) & 7, qb = qa ^ 4;
        const float4 xa = *(const float4*)(xg + bb * 2048 + i * 32 + qa * 4);
        const float4 sa = *(const float4*)(Sl + bb * 32 + qa * 4);
        const float4 xv2 = *(const float4*)(xg + bb * 2048 + i * 32 + qb * 4);
        const float4 sb = *(const float4*)(Sl + bb * 32 + qb * 4);
        float s = xa.x * sa.x + xa.y * sa.y + xa.z * sa.z + xa.w * sa.w
                + xv2.x * sb.x + xv2.y * sb.y + xv2.z * sb.z + xv2.w * sb.w;
        s = dpp_add<0x111>(s);
        s = dpp_add<0x112>(s);
        if (h == 3) {
            const float e2 = __expf(2.0f * s);
            out[(bbase + (long long)tp * GR + bb) * 64 + i] = 1.0f - 2.0f / (e2 + 1.0f);
        }
    }
    #undef STAGE
}

extern "C" void kernel_launch(void* const* d_in, const int* in_sizes, int n_in,
                              void* d_out, int out_size, void* d_ws, size_t ws_size,
                              hipStream_t stream) {
    const float* x = (const float*)d_in[0];   // [65536,64,32] fp32
    const float* W = (const float*)d_in[1];   // [64,32,32] fp32
    float* out = (float*)d_out;               // [65536,64] fp32
    float* W6  = (float*)d_ws;                // 65536 floats = 256 KB scratch

    const size_t smem_bytes = (size_t)(4 * 8192 + 128 * PST + 128) * sizeof(float); // 141824
    hipFuncSetAttribute((const void*)ipf_kernel,
                        hipFuncAttributeMaxDynamicSharedMemorySize, (int)smem_bytes);

    wtrans_kernel<<<64, 1024, 0, stream>>>(W, W6);
    ipf_kernel<<<NBLK, 1024, smem_bytes, stream>>>(x, W6, out);
}